// Round 4
// baseline (203.475 us; speedup 1.0000x reference)
//
#include <hip/hip_runtime.h>

#define N_NODES 100000
#define DEG 16
#define D_DIM 128
#define U_DIM 128

typedef __bf16 bf16x8 __attribute__((ext_vector_type(8)));
typedef float f32x4 __attribute__((ext_vector_type(4)));
typedef unsigned int u32x4 __attribute__((ext_vector_type(4)));

__device__ __forceinline__ unsigned short f2bf(float x) {
    // round-to-nearest-even fp32 -> bf16 (inputs finite)
    unsigned int u = __float_as_uint(x);
    u += 0x7fffu + ((u >> 16) & 1u);
    return (unsigned short)(u >> 16);
}
__device__ __forceinline__ unsigned int pack2(float a, float b) {
    return (unsigned int)f2bf(a) | ((unsigned int)f2bf(b) << 16);
}

// W fp32 [K=128][U=128] row-major -> WT bf16 [U][K] (A-fragment friendly: k contiguous)
__global__ void cast_w_kernel(const float* __restrict__ W,
                              unsigned short* __restrict__ WT) {
    int t = blockIdx.x * 256 + threadIdx.x;   // t < 16384
    int k = t >> 7, n = t & 127;
    WT[n * 128 + k] = f2bf(W[t]);
}

// Y[n][u] = feat[n,:] @ W[:,u] + b[u], stored bf16 row-major [N][128].
// v2: NO LDS. K=128 fits in registers: B-fragments loaded straight from feat
// (f32, two float4 per kc; a wave's instr touches 16 full 128B lines), cast
// in-reg with the same f2bf rounding (Y bit-identical to the LDS version).
// A = W^T loop-invariant fragments (WT is 32 KB, L1/L2-hot across all blocks).
// Old version: 782 blocks x 34 KB LDS = ~3 blocks/CU, ONE occupancy round ->
// duration ~ one block's serial stage latency. v2: 6250 blocks, 24 rounds/CU,
// zero barriers; should run at the streaming floor (~77 MB / ~5.5 TB/s).
__global__ __launch_bounds__(256, 4)
void ymat_kernel(const float* __restrict__ feat,
                 const unsigned short* __restrict__ WT,   // bf16 [U][K]
                 const float* __restrict__ bias,
                 unsigned short* __restrict__ Y) {
    const int lane = threadIdx.x & 63;
    const int wv = threadIdx.x >> 6;
    const int quad = lane >> 4;
    const int l15 = lane & 15;
    const int node = blockIdx.x * 16 + l15;   // exact: 6250*16 = N_NODES
    const int u_base = wv * 32;

    // ---- B fragments from global: row=node, k = kc*32 + quad*8 + j
    const float* frow = feat + (size_t)node * D_DIM;
    float4 f0[4], f1[4];
    #pragma unroll
    for (int kc = 0; kc < 4; ++kc) {
        f0[kc] = *(const float4*)(frow + kc * 32 + quad * 8);
        f1[kc] = *(const float4*)(frow + kc * 32 + quad * 8 + 4);
    }

    // ---- A fragments: A[m=l15 -> u][k = kc*32+quad*8+j] (all 4 waves share WT in L1)
    bf16x8 afr[2][4];
    #pragma unroll
    for (int ni = 0; ni < 2; ++ni) {
        const int u = u_base + ni * 16 + l15;
        #pragma unroll
        for (int kc = 0; kc < 4; ++kc)
            afr[ni][kc] = *(const bf16x8*)(WT + u * 128 + kc * 32 + quad * 8);
    }
    // bias for D rows: u = u_base + ni*16 + quad*4 + r
    const float4 bv0 = *(const float4*)(bias + u_base + quad * 4);
    const float4 bv1 = *(const float4*)(bias + u_base + 16 + quad * 4);

    // ---- convert B to bf16 fragments (same rounding as before: Y bit-identical)
    bf16x8 bfr[4];
    #pragma unroll
    for (int kc = 0; kc < 4; ++kc) {
        u32x4 t;
        t[0] = pack2(f0[kc].x, f0[kc].y);
        t[1] = pack2(f0[kc].z, f0[kc].w);
        t[2] = pack2(f1[kc].x, f1[kc].y);
        t[3] = pack2(f1[kc].z, f1[kc].w);
        bfr[kc] = __builtin_bit_cast(bf16x8, t);
    }

    f32x4 acc0 = (f32x4){0.f, 0.f, 0.f, 0.f};
    f32x4 acc1 = (f32x4){0.f, 0.f, 0.f, 0.f};
    #pragma unroll
    for (int kc = 0; kc < 4; ++kc) {
        acc0 = __builtin_amdgcn_mfma_f32_16x16x32_bf16(afr[0][kc], bfr[kc], acc0, 0, 0, 0);
        acc1 = __builtin_amdgcn_mfma_f32_16x16x32_bf16(afr[1][kc], bfr[kc], acc1, 0, 0, 0);
    }

    unsigned int* yp = (unsigned int*)(Y + (size_t)node * U_DIM + u_base + quad * 4);
    uint2 s0, s1;
    s0.x = pack2(acc0[0] + bv0.x, acc0[1] + bv0.y);
    s0.y = pack2(acc0[2] + bv0.z, acc0[3] + bv0.w);
    s1.x = pack2(acc1[0] + bv1.x, acc1[1] + bv1.y);
    s1.y = pack2(acc1[2] + bv1.z, acc1[3] + bv1.w);
    *(uint2*)yp = s0;
    *(uint2*)(yp + 8) = s1;   // +16 ushorts
}

// out[n, phase*64 : +64] = relu( (sum_e w_e * Y[col_e, half]) / (sum_e w_e) )
// Two u-phases via grid ordering (12.8 MB pool/phase). 8 lanes/node, uint4
// gathers: one instr = 8 nodes x full 128 B half-row (aligned, fully-used lines).
// CEILING EVIDENCE: three schedules (4-deep re-rolled VGPR=36, 16-deep uint2,
// asm-pinned 16-deep VGPR=48 / occ 42%) all land at 3.73-3.84 TB/s, 56.8-58.2 us
// -> pattern-bandwidth-bound (random 128B-line L2-fill fabric), not latency/MLP.
__global__ __launch_bounds__(256, 4)
void agg_kernel(const unsigned short* __restrict__ Y,
                const int* __restrict__ cols,
                const float* __restrict__ wts,
                float* __restrict__ out) {
    const int phase = (blockIdx.x >= 3125) ? 1 : 0;
    const int nb = blockIdx.x - phase * 3125;
    const int node = nb * 32 + (threadIdx.x >> 3);   // exact: 3125*32 = N_NODES
    const int ubase = phase * 64 + (threadIdx.x & 7) * 8;   // owns 8 dims
    const int e0 = node * DEG;

    int cc[DEG];
    float ww[DEG];
    #pragma unroll
    for (int q = 0; q < 4; ++q) {
        const int4 c4 = *(const int4*)(cols + e0 + 4 * q);
        const float4 w4 = *(const float4*)(wts + e0 + 4 * q);
        cc[4 * q + 0] = c4.x; cc[4 * q + 1] = c4.y;
        cc[4 * q + 2] = c4.z; cc[4 * q + 3] = c4.w;
        ww[4 * q + 0] = w4.x; ww[4 * q + 1] = w4.y;
        ww[4 * q + 2] = w4.z; ww[4 * q + 3] = w4.w;
    }
    float den = 0.f;
    #pragma unroll
    for (int e = 0; e < DEG; ++e) den += ww[e];

    // ---- 16 gathers pinned in flight via volatile asm (fastest measured variant)
    const unsigned short* ybase = Y + ubase;
    u32x4 p[DEG];
    #pragma unroll
    for (int e = 0; e < DEG; ++e) {
        const unsigned long long a =
            (unsigned long long)(ybase + (size_t)cc[e] * U_DIM);
        asm volatile("global_load_dwordx4 %0, %1, off" : "=v"(p[e]) : "v"(a));
    }
    asm volatile("s_waitcnt vmcnt(0)" ::: "memory");
    __builtin_amdgcn_sched_barrier(0);   // rule #18: no consumer hoists above the wait

    float a0 = 0.f, a1 = 0.f, a2 = 0.f, a3 = 0.f;
    float a4 = 0.f, a5 = 0.f, a6 = 0.f, a7 = 0.f;
    #pragma unroll
    for (int e = 0; e < DEG; ++e) {
        const float w = ww[e];
        a0 = fmaf(w, __uint_as_float(p[e][0] << 16), a0);
        a1 = fmaf(w, __uint_as_float(p[e][0] & 0xffff0000u), a1);
        a2 = fmaf(w, __uint_as_float(p[e][1] << 16), a2);
        a3 = fmaf(w, __uint_as_float(p[e][1] & 0xffff0000u), a3);
        a4 = fmaf(w, __uint_as_float(p[e][2] << 16), a4);
        a5 = fmaf(w, __uint_as_float(p[e][2] & 0xffff0000u), a5);
        a6 = fmaf(w, __uint_as_float(p[e][3] << 16), a6);
        a7 = fmaf(w, __uint_as_float(p[e][3] & 0xffff0000u), a7);
    }
    const float inv = 1.0f / den;           // den >= 0.1*16
    f32x4 o0, o1;
    o0[0] = fmaxf(a0 * inv, 0.f); o0[1] = fmaxf(a1 * inv, 0.f);
    o0[2] = fmaxf(a2 * inv, 0.f); o0[3] = fmaxf(a3 * inv, 0.f);
    o1[0] = fmaxf(a4 * inv, 0.f); o1[1] = fmaxf(a5 * inv, 0.f);
    o1[2] = fmaxf(a6 * inv, 0.f); o1[3] = fmaxf(a7 * inv, 0.f);
    f32x4* op = (f32x4*)(out + (size_t)node * U_DIM + ubase);
    __builtin_nontemporal_store(o0, op);    // write-once stream: don't evict Y from L2
    __builtin_nontemporal_store(o1, op + 1);
}

extern "C" void kernel_launch(void* const* d_in, const int* in_sizes, int n_in,
                              void* d_out, int out_size, void* d_ws, size_t ws_size,
                              hipStream_t stream) {
    const float* feat = (const float*)d_in[0];
    // d_in[1] = edge_rows: unused — rows are arange(E)//DEG, node i owns edges [16i,16i+16)
    const int* cols  = (const int*)d_in[2];
    const float* wts = (const float*)d_in[3];
    const float* W   = (const float*)d_in[4];
    const float* b   = (const float*)d_in[5];
    float* out = (float*)d_out;

    unsigned short* wt_bf = (unsigned short*)d_ws;                    // 32 KB bf16 [U][K]
    unsigned short* Y     = (unsigned short*)((char*)d_ws + 32768);   // 25.6 MB bf16 [N][128]

    cast_w_kernel<<<16384 / 256, 256, 0, stream>>>(W, wt_bf);

    ymat_kernel<<<N_NODES / 16, 256, 0, stream>>>(feat, wt_bf, b, Y);   // 6250 blocks

    agg_kernel<<<6250, 256, 0, stream>>>(Y, cols, wts, out);
}

// Round 5
// 190.764 us; speedup vs baseline: 1.0666x; 1.0666x over previous
//
#include <hip/hip_runtime.h>

#define N_NODES 100000
#define N_HALF 50000
#define DEG 16
#define D_DIM 128
#define U_DIM 128
#define FSTRIDE 136   // bf16 LDS row stride: 272 B -> 68 dwords -> conflicts <= 2-way

typedef __bf16 bf16x8 __attribute__((ext_vector_type(8)));
typedef float f32x4 __attribute__((ext_vector_type(4)));

__device__ __forceinline__ unsigned short f2bf(float x) {
    // round-to-nearest-even fp32 -> bf16 (inputs finite)
    unsigned int u = __float_as_uint(x);
    u += 0x7fffu + ((u >> 16) & 1u);
    return (unsigned short)(u >> 16);
}
__device__ __forceinline__ unsigned int pack2(float a, float b) {
    return (unsigned int)f2bf(a) | ((unsigned int)f2bf(b) << 16);
}

// W fp32 [K=128][U=128] row-major -> WT bf16 [U][K] (A-fragment friendly: k contiguous)
__global__ void cast_w_kernel(const float* __restrict__ W,
                              unsigned short* __restrict__ WT) {
    int t = blockIdx.x * 256 + threadIdx.x;   // t < 16384
    int k = t >> 7, n = t & 127;
    WT[n * 128 + k] = f2bf(W[t]);
}

// Y[n][u] = feat[n,:] @ W[:,u] + b[u], stored bf16 row-major [N][128].
// PROVEN LDS version (R2, total 175.6): feat tile (128 nodes) staged ONCE per
// block as bf16; A = W^T loop-invariant fragments; B via ds_read_b128.
// (R4's no-LDS variant was +28 us: 4x redundant per-wave feat/WT re-reads.)
__global__ __launch_bounds__(256)
void ymat_kernel(const float* __restrict__ feat,
                 const unsigned short* __restrict__ WT,   // bf16 [U][K]
                 const float* __restrict__ bias,
                 unsigned short* __restrict__ Y) {
    __shared__ __align__(16) unsigned short ftile[128 * FSTRIDE];
    const int lane = threadIdx.x & 63;
    const int wv = threadIdx.x >> 6;
    const int quad = lane >> 4;
    const int l15 = lane & 15;
    const int n0 = blockIdx.x * 128;
    const int u_base = wv * 32;

    // ---- stage: 16384 floats, thread t handles float4 indices j*256+t (1 KB/instr/wave)
    {
        const int t = threadIdx.x;
        #pragma unroll
        for (int j = 0; j < 16; ++j) {
            const int i = j * 256 + t;          // float4 index in tile
            const int row = i >> 5;
            const int col = (i & 31) * 4;
            const int rowc = (n0 + row < N_NODES) ? (n0 + row) : (N_NODES - 1);
            const float4 v = *(const float4*)(feat + (size_t)rowc * D_DIM + col);
            ushort4 s;
            s.x = f2bf(v.x); s.y = f2bf(v.y); s.z = f2bf(v.z); s.w = f2bf(v.w);
            *(ushort4*)&ftile[row * FSTRIDE + col] = s;
        }
    }

    // A fragments: A[m=l15 -> u][k = kc*32+quad*8+j]
    bf16x8 afr[2][4];
    #pragma unroll
    for (int ni = 0; ni < 2; ++ni) {
        const int u = u_base + ni * 16 + l15;
        #pragma unroll
        for (int kc = 0; kc < 4; ++kc)
            afr[ni][kc] = *(const bf16x8*)(WT + u * 128 + kc * 32 + quad * 8);
    }
    // bias for D rows: u = u_base + ni*16 + quad*4 + r
    const float4 bv0 = *(const float4*)(bias + u_base + quad * 4);
    const float4 bv1 = *(const float4*)(bias + u_base + 16 + quad * 4);

    __syncthreads();

    #pragma unroll
    for (int mi = 0; mi < 8; ++mi) {
        const int node = n0 + mi * 16 + l15;
        bf16x8 bfr[4];
        #pragma unroll
        for (int kc = 0; kc < 4; ++kc)   // B[k][n]: n=l15 -> node row in LDS
            bfr[kc] = *(const bf16x8*)&ftile[(mi * 16 + l15) * FSTRIDE + kc * 32 + quad * 8];
        f32x4 acc0 = (f32x4){0.f, 0.f, 0.f, 0.f};
        f32x4 acc1 = (f32x4){0.f, 0.f, 0.f, 0.f};
        #pragma unroll
        for (int kc = 0; kc < 4; ++kc) {
            acc0 = __builtin_amdgcn_mfma_f32_16x16x32_bf16(afr[0][kc], bfr[kc], acc0, 0, 0, 0);
            acc1 = __builtin_amdgcn_mfma_f32_16x16x32_bf16(afr[1][kc], bfr[kc], acc1, 0, 0, 0);
        }
        if (node < N_NODES) {
            unsigned int* yp = (unsigned int*)(Y + (size_t)node * U_DIM + u_base + quad * 4);
            uint2 s0, s1;
            s0.x = pack2(acc0[0] + bv0.x, acc0[1] + bv0.y);
            s0.y = pack2(acc0[2] + bv0.z, acc0[3] + bv0.w);
            s1.x = pack2(acc1[0] + bv1.x, acc1[1] + bv1.y);
            s1.y = pack2(acc1[2] + bv1.z, acc1[3] + bv1.w);
            *(uint2*)yp = s0;
            *(uint2*)(yp + 8) = s1;   // +16 ushorts
        }
    }
}

// out[n, phase*64 : +64] = relu( (sum_e w_e * Y[col_e, half]) / (sum_e w_e) )
// Grid: 2 U-phases (64 dims each). NEW: 2 col-ROUNDS inside each block —
// round 0 gathers only edges with col < 50000, round 1 the rest. Live pool
// per (phase,round) = 50000 x 64dims x 2B = 6.4 MB (was 12.8) vs 4 MB/XCD L2.
// Rounds separated by s_barrier + sched_barrier so neither compiler nor waves
// mix them. Each edge processed exactly once (exact predicate partition);
// inactive p[e] zeroed so unmasked FMAs add 0. MLP/schedule insensitivity
// proven in R0-R3 (three schedules, identical 3.8 TB/s), so predication and
// compiler re-rolling are harmless; only miss VOLUME matters.
__global__ __launch_bounds__(256, 4)
void agg_kernel(const unsigned short* __restrict__ Y,
                const int* __restrict__ cols,
                const float* __restrict__ wts,
                float* __restrict__ out) {
    const int phase = (blockIdx.x >= 6250) ? 1 : 0;
    const int nb = blockIdx.x - phase * 6250;
    const int node = nb * 16 + (threadIdx.x >> 4);   // exact: 6250*16 = N_NODES
    const int ubase = phase * 64 + (threadIdx.x & 15) * 4;   // owns 4 dims
    const int e0 = node * DEG;

    int cc[DEG];
    float ww[DEG];
    #pragma unroll
    for (int q = 0; q < 4; ++q) {
        const int4 c4 = *(const int4*)(cols + e0 + 4 * q);
        const float4 w4 = *(const float4*)(wts + e0 + 4 * q);
        cc[4 * q + 0] = c4.x; cc[4 * q + 1] = c4.y;
        cc[4 * q + 2] = c4.z; cc[4 * q + 3] = c4.w;
        ww[4 * q + 0] = w4.x; ww[4 * q + 1] = w4.y;
        ww[4 * q + 2] = w4.z; ww[4 * q + 3] = w4.w;
    }
    float den = 0.f;
    #pragma unroll
    for (int e = 0; e < DEG; ++e) den += ww[e];

    const unsigned short* yb = Y + ubase;
    float a0 = 0.f, a1 = 0.f, a2 = 0.f, a3 = 0.f;
    uint2 p[DEG];

    // ---- round 0: cols in [0, N_HALF) — pool = Y rows 0..50000, this u-half
    #pragma unroll
    for (int e = 0; e < DEG; ++e) {
        p[e].x = 0u; p[e].y = 0u;
        if (cc[e] < N_HALF)
            p[e] = *(const uint2*)(yb + (size_t)cc[e] * U_DIM);
    }
    #pragma unroll
    for (int e = 0; e < DEG; ++e) {      // inactive p[e]=0 -> contributes 0
        const float w = ww[e];
        a0 = fmaf(w, __uint_as_float(p[e].x << 16), a0);
        a1 = fmaf(w, __uint_as_float(p[e].x & 0xffff0000u), a1);
        a2 = fmaf(w, __uint_as_float(p[e].y << 16), a2);
        a3 = fmaf(w, __uint_as_float(p[e].y & 0xffff0000u), a3);
    }

    __builtin_amdgcn_s_barrier();        // keep the block's waves in round-phase
    __builtin_amdgcn_sched_barrier(0);   // forbid hoisting round-1 loads into round 0

    // ---- round 1: cols in [N_HALF, N) — the other 6.4 MB pool
    #pragma unroll
    for (int e = 0; e < DEG; ++e) {
        if (cc[e] >= N_HALF)
            p[e] = *(const uint2*)(yb + (size_t)cc[e] * U_DIM);
        else { p[e].x = 0u; p[e].y = 0u; }   // mask out round-0 leftovers
    }
    #pragma unroll
    for (int e = 0; e < DEG; ++e) {
        const float w = ww[e];
        a0 = fmaf(w, __uint_as_float(p[e].x << 16), a0);
        a1 = fmaf(w, __uint_as_float(p[e].x & 0xffff0000u), a1);
        a2 = fmaf(w, __uint_as_float(p[e].y << 16), a2);
        a3 = fmaf(w, __uint_as_float(p[e].y & 0xffff0000u), a3);
    }

    const float inv = 1.0f / den;           // den >= 0.1*16
    f32x4 o;
    o[0] = fmaxf(a0 * inv, 0.f); o[1] = fmaxf(a1 * inv, 0.f);
    o[2] = fmaxf(a2 * inv, 0.f); o[3] = fmaxf(a3 * inv, 0.f);
    __builtin_nontemporal_store(o, (f32x4*)(out + (size_t)node * U_DIM + ubase));
}

extern "C" void kernel_launch(void* const* d_in, const int* in_sizes, int n_in,
                              void* d_out, int out_size, void* d_ws, size_t ws_size,
                              hipStream_t stream) {
    const float* feat = (const float*)d_in[0];
    // d_in[1] = edge_rows: unused — rows are arange(E)//DEG, node i owns edges [16i,16i+16)
    const int* cols  = (const int*)d_in[2];
    const float* wts = (const float*)d_in[3];
    const float* W   = (const float*)d_in[4];
    const float* b   = (const float*)d_in[5];
    float* out = (float*)d_out;

    unsigned short* wt_bf = (unsigned short*)d_ws;                    // 32 KB bf16 [U][K]
    unsigned short* Y     = (unsigned short*)((char*)d_ws + 32768);   // 25.6 MB bf16 [N][128]

    cast_w_kernel<<<16384 / 256, 256, 0, stream>>>(W, wt_bf);

    const int nblocks = (N_NODES + 127) / 128;   // 782
    ymat_kernel<<<nblocks, 256, 0, stream>>>(feat, wt_bf, b, Y);

    agg_kernel<<<12500, 256, 0, stream>>>(Y, cols, wts, out);
}

// Round 6
// 174.419 us; speedup vs baseline: 1.1666x; 1.0937x over previous
//
#include <hip/hip_runtime.h>

#define N_NODES 100000
#define DEG 16
#define D_DIM 128
#define U_DIM 128
#define TILE 64       // ymat node tile: 1563 blocks -> ~1.5 occupancy rounds (was 782 = single round)
#define FSTRIDE 136   // bf16 LDS row stride: 272 B -> 68 dwords -> conflicts <= 2-way

typedef __bf16 bf16x8 __attribute__((ext_vector_type(8)));
typedef float f32x4 __attribute__((ext_vector_type(4)));

__device__ __forceinline__ unsigned short f2bf(float x) {
    // round-to-nearest-even fp32 -> bf16 (inputs finite)
    unsigned int u = __float_as_uint(x);
    u += 0x7fffu + ((u >> 16) & 1u);
    return (unsigned short)(u >> 16);
}
__device__ __forceinline__ unsigned int pack2(float a, float b) {
    return (unsigned int)f2bf(a) | ((unsigned int)f2bf(b) << 16);
}

// W fp32 [K=128][U=128] row-major -> WT bf16 [U][K] (A-fragment friendly: k contiguous)
__global__ void cast_w_kernel(const float* __restrict__ W,
                              unsigned short* __restrict__ WT) {
    int t = blockIdx.x * 256 + threadIdx.x;   // t < 16384
    int k = t >> 7, n = t & 127;
    WT[n * 128 + k] = f2bf(W[t]);
}

// Y[n][u] = feat[n,:] @ W[:,u] + b[u], stored bf16 row-major [N][128].
// Proven LDS structure (R2); tile shrunk 128->64 nodes: 782 blocks was a SINGLE
// occupancy round (all resident), so kernel time ~ one block's serial
// stage->barrier->compute chain. 1563 blocks / 17 KB LDS pipelines across
// ~1.5 rounds with twice the blocks/CU. Y remains bit-identical.
__global__ __launch_bounds__(256)
void ymat_kernel(const float* __restrict__ feat,
                 const unsigned short* __restrict__ WT,   // bf16 [U][K]
                 const float* __restrict__ bias,
                 unsigned short* __restrict__ Y) {
    __shared__ __align__(16) unsigned short ftile[TILE * FSTRIDE];
    const int lane = threadIdx.x & 63;
    const int wv = threadIdx.x >> 6;
    const int quad = lane >> 4;
    const int l15 = lane & 15;
    const int n0 = blockIdx.x * TILE;
    const int u_base = wv * 32;

    // ---- stage: TILE*128 floats = 2048 float4s, thread t handles j*256+t
    {
        const int t = threadIdx.x;
        #pragma unroll
        for (int j = 0; j < 8; ++j) {
            const int i = j * 256 + t;          // float4 index in tile
            const int row = i >> 5;
            const int col = (i & 31) * 4;
            const int rowc = (n0 + row < N_NODES) ? (n0 + row) : (N_NODES - 1);
            const float4 v = *(const float4*)(feat + (size_t)rowc * D_DIM + col);
            ushort4 s;
            s.x = f2bf(v.x); s.y = f2bf(v.y); s.z = f2bf(v.z); s.w = f2bf(v.w);
            *(ushort4*)&ftile[row * FSTRIDE + col] = s;
        }
    }

    // A fragments: A[m=l15 -> u][k = kc*32+quad*8+j]
    bf16x8 afr[2][4];
    #pragma unroll
    for (int ni = 0; ni < 2; ++ni) {
        const int u = u_base + ni * 16 + l15;
        #pragma unroll
        for (int kc = 0; kc < 4; ++kc)
            afr[ni][kc] = *(const bf16x8*)(WT + u * 128 + kc * 32 + quad * 8);
    }
    // bias for D rows: u = u_base + ni*16 + quad*4 + r
    const float4 bv0 = *(const float4*)(bias + u_base + quad * 4);
    const float4 bv1 = *(const float4*)(bias + u_base + 16 + quad * 4);

    __syncthreads();

    #pragma unroll
    for (int mi = 0; mi < TILE / 16; ++mi) {
        const int node = n0 + mi * 16 + l15;
        bf16x8 bfr[4];
        #pragma unroll
        for (int kc = 0; kc < 4; ++kc)   // B[k][n]: n=l15 -> node row in LDS
            bfr[kc] = *(const bf16x8*)&ftile[(mi * 16 + l15) * FSTRIDE + kc * 32 + quad * 8];
        f32x4 acc0 = (f32x4){0.f, 0.f, 0.f, 0.f};
        f32x4 acc1 = (f32x4){0.f, 0.f, 0.f, 0.f};
        #pragma unroll
        for (int kc = 0; kc < 4; ++kc) {
            acc0 = __builtin_amdgcn_mfma_f32_16x16x32_bf16(afr[0][kc], bfr[kc], acc0, 0, 0, 0);
            acc1 = __builtin_amdgcn_mfma_f32_16x16x32_bf16(afr[1][kc], bfr[kc], acc1, 0, 0, 0);
        }
        if (node < N_NODES) {
            unsigned int* yp = (unsigned int*)(Y + (size_t)node * U_DIM + u_base + quad * 4);
            uint2 s0, s1;
            s0.x = pack2(acc0[0] + bv0.x, acc0[1] + bv0.y);
            s0.y = pack2(acc0[2] + bv0.z, acc0[3] + bv0.w);
            s1.x = pack2(acc1[0] + bv1.x, acc1[1] + bv1.y);
            s1.y = pack2(acc1[2] + bv1.z, acc1[3] + bv1.w);
            *(uint2*)yp = s0;
            *(uint2*)(yp + 8) = s1;   // +16 ushorts
        }
    }
}

// out[n, phase*64 : +64] = relu( (sum_e w_e * Y[col_e, half]) / (sum_e w_e) )
// R2-EXACT version (session best: total 175.58). CEILING EVIDENCE: four agg
// variants (4-deep re-rolled VGPR=36 / 16-deep uint2 / asm-pinned VGPR=48,
// occ 42% / col-rounds) all fetch ~158 MB; the three sane schedules land at
// 3.73-3.84 TB/s, 56.8-58.2 us across occupancy 38-58% -> pattern-bandwidth
// ceiling for random 128B-line gathers (cross-XCD L2 duplication compulsory).
// Col-round pool-split (R5) changed FETCH by 0 and cost +17 us: reverted.
__global__ __launch_bounds__(256, 4)
void agg_kernel(const unsigned short* __restrict__ Y,
                const int* __restrict__ cols,
                const float* __restrict__ wts,
                float* __restrict__ out) {
    const int phase = (blockIdx.x >= 6250) ? 1 : 0;
    const int nb = blockIdx.x - phase * 6250;
    const int node = nb * 16 + (threadIdx.x >> 4);   // exact: 6250*16 = N_NODES
    const int ubase = phase * 64 + (threadIdx.x & 15) * 4;   // owns 4 dims
    const int e0 = node * DEG;

    int cc[DEG];
    float ww[DEG];
    #pragma unroll
    for (int q = 0; q < 4; ++q) {
        const int4 c4 = *(const int4*)(cols + e0 + 4 * q);
        const float4 w4 = *(const float4*)(wts + e0 + 4 * q);
        cc[4 * q + 0] = c4.x; cc[4 * q + 1] = c4.y;
        cc[4 * q + 2] = c4.z; cc[4 * q + 3] = c4.w;
        ww[4 * q + 0] = w4.x; ww[4 * q + 1] = w4.y;
        ww[4 * q + 2] = w4.z; ww[4 * q + 3] = w4.w;
    }

    uint2 p[DEG];
    #pragma unroll
    for (int e = 0; e < DEG; ++e)
        p[e] = *(const uint2*)(Y + (size_t)cc[e] * U_DIM + ubase);
    __builtin_amdgcn_sched_barrier(0);

    float den = 0.f;
    #pragma unroll
    for (int e = 0; e < DEG; ++e) den += ww[e];

    float a0 = 0.f, a1 = 0.f, a2 = 0.f, a3 = 0.f;
    #pragma unroll
    for (int e = 0; e < DEG; ++e) {
        const float w = ww[e];
        a0 = fmaf(w, __uint_as_float(p[e].x << 16), a0);
        a1 = fmaf(w, __uint_as_float(p[e].x & 0xffff0000u), a1);
        a2 = fmaf(w, __uint_as_float(p[e].y << 16), a2);
        a3 = fmaf(w, __uint_as_float(p[e].y & 0xffff0000u), a3);
    }
    const float inv = 1.0f / den;           // den >= 0.1*16
    f32x4 o;
    o[0] = fmaxf(a0 * inv, 0.f); o[1] = fmaxf(a1 * inv, 0.f);
    o[2] = fmaxf(a2 * inv, 0.f); o[3] = fmaxf(a3 * inv, 0.f);
    __builtin_nontemporal_store(o, (f32x4*)(out + (size_t)node * U_DIM + ubase));
}

extern "C" void kernel_launch(void* const* d_in, const int* in_sizes, int n_in,
                              void* d_out, int out_size, void* d_ws, size_t ws_size,
                              hipStream_t stream) {
    const float* feat = (const float*)d_in[0];
    // d_in[1] = edge_rows: unused — rows are arange(E)//DEG, node i owns edges [16i,16i+16)
    const int* cols  = (const int*)d_in[2];
    const float* wts = (const float*)d_in[3];
    const float* W   = (const float*)d_in[4];
    const float* b   = (const float*)d_in[5];
    float* out = (float*)d_out;

    unsigned short* wt_bf = (unsigned short*)d_ws;                    // 32 KB bf16 [U][K]
    unsigned short* Y     = (unsigned short*)((char*)d_ws + 32768);   // 25.6 MB bf16 [N][128]

    cast_w_kernel<<<16384 / 256, 256, 0, stream>>>(W, wt_bf);

    const int nblocks = (N_NODES + TILE - 1) / TILE;   // 1563
    ymat_kernel<<<nblocks, 256, 0, stream>>>(feat, wt_bf, b, Y);

    agg_kernel<<<12500, 256, 0, stream>>>(Y, cols, wts, out);
}